// Round 2
// baseline (816.166 us; speedup 1.0000x reference)
//
#include <hip/hip_runtime.h>
#include <math.h>

#define NTOK 131072   // 16 * 8192 tokens
#define D    64       // embedding dim
#define DP   68       // padded LDS stride: 4 mod 32 -> 2-way-max b128 conflicts, 16B aligned
#define K    1024     // codebook size
#define MT   64       // tokens per block
#define NC   128      // codes per chunk
#define NCH  (K/NC)   // 8 chunks

typedef float nfloat4 __attribute__((ext_vector_type(4)));  // native vec for nontemporal builtins

__global__ __launch_bounds__(256) void vq_norms(const float* __restrict__ cb,
                                                float* __restrict__ ne,
                                                float* __restrict__ rne) {
  int k = blockIdx.x * 256 + threadIdx.x;
  if (k >= K) return;
  const float4* p = (const float4*)(cb + (size_t)k * D);
  float s = 0.f;
#pragma unroll
  for (int i = 0; i < D / 4; ++i) {
    float4 v = p[i];
    s += v.x * v.x; s += v.y * v.y; s += v.z * v.z; s += v.w * v.w;
  }
  ne[k] = s;
  rne[k] = 1.0f / sqrtf(s);
}

__global__ __launch_bounds__(256) void vq_main(const float* __restrict__ z,
                                               const float* __restrict__ cb,
                                               const float* __restrict__ g_ne,
                                               const float* __restrict__ g_rne,
                                               float* __restrict__ e_out,
                                               float* __restrict__ zq_out,
                                               float* __restrict__ sim_out,
                                               float* __restrict__ loss_out) {
  __shared__ float zs[MT][DP];    // 64 x 68 z tile
  __shared__ float es[NC][DP];    // 128 x 68 codebook chunk (reused for argmin reduce)
  __shared__ float ne_s[NC];
  __shared__ float rne_s[NC];
  __shared__ float nz_s[MT];
  __shared__ float rnz_s[MT];
  __shared__ int   e_s[MT];
  __shared__ float lpart[MT][4];

  const int tid = threadIdx.x;
  const int tx = tid & 15;   // code-column group
  const int ty = tid >> 4;   // token-row group
  const int tok0 = blockIdx.x * MT;

  // ---- stage z tile (coalesced float4) ----
  {
    const float* zb = z + (size_t)tok0 * D;
#pragma unroll
    for (int i = 0; i < 4; ++i) {
      int g = tid * 4 + i * 1024;
      int r = g >> 6, c = g & 63;
      *(float4*)&zs[r][c] = *(const float4*)&zb[g];
    }
  }
  __syncthreads();
  // per-token ||z||^2 and 1/||z||
  if (tid < MT) {
    float s = 0.f;
#pragma unroll
    for (int i = 0; i < D / 4; ++i) {
      float4 v = *(const float4*)&zs[tid][i * 4];
      s += v.x * v.x; s += v.y * v.y; s += v.z * v.z; s += v.w * v.w;
    }
    nz_s[tid] = s;
    rnz_s[tid] = 1.0f / sqrtf(s);
  }

  float bestd[4];
  int   besti[4];
#pragma unroll
  for (int i = 0; i < 4; ++i) { bestd[i] = INFINITY; besti[i] = 0; }

  for (int ch = 0; ch < NCH; ++ch) {
    __syncthreads();  // previous chunk's reads of es/ne_s done (also covers nz_s for ch=0)
    {
      const float* eb = cb + (size_t)ch * NC * D;
#pragma unroll
      for (int i = 0; i < 8; ++i) {
        int g = tid * 4 + i * 1024;
        int r = g >> 6, c = g & 63;
        *(float4*)&es[r][c] = *(const float4*)&eb[g];
      }
      if (tid < NC)            ne_s[tid]        = g_ne[ch * NC + tid];
      else if (tid < 2 * NC)   rne_s[tid - NC]  = g_rne[ch * NC + tid - NC];
    }
    __syncthreads();

    float dot[4][8];
#pragma unroll
    for (int i = 0; i < 4; ++i)
#pragma unroll
      for (int j = 0; j < 8; ++j) dot[i][j] = 0.f;

    // K=64 reduction, 4 at a time via b128 LDS reads; 32 independent FMA chains
#pragma unroll
    for (int k = 0; k < D; k += 4) {
      float4 a[4], b[8];
#pragma unroll
      for (int i = 0; i < 4; ++i) a[i] = *(const float4*)&zs[ty * 4 + i][k];
#pragma unroll
      for (int j = 0; j < 8; ++j) b[j] = *(const float4*)&es[tx + 16 * j][k];
#pragma unroll
      for (int i = 0; i < 4; ++i)
#pragma unroll
        for (int j = 0; j < 8; ++j)
          dot[i][j] += a[i].x * b[j].x + a[i].y * b[j].y + a[i].z * b[j].z + a[i].w * b[j].w;
    }

    // epilogue: sim writes (nontemporal; don't evict L2 codebook) + argmin update
#pragma unroll
    for (int i = 0; i < 4; ++i) {
      const int tl = ty * 4 + i;
      const float nz = nz_s[tl];
      const float rnz = rnz_s[tl];
      float* simrow = sim_out + (size_t)(tok0 + tl) * K + ch * NC;
#pragma unroll
      for (int j = 0; j < 8; ++j) {
        const int cl = tx + 16 * j;
        float dd = dot[i][j];
        // mimic np rounding pipeline: m = fl(-2*dot + ne); dist = fl(nz + m)
        float m = fmaf(-2.f, dd, ne_s[cl]);
        float dst = nz + m;
        __builtin_nontemporal_store(dd * rnz * rne_s[cl], simrow + cl);
        if (dst < bestd[i]) { bestd[i] = dst; besti[i] = ch * NC + cl; }  // ascending c -> first-min kept
      }
    }
  }

  __syncthreads();
  // cross-thread argmin reduce (lexicographic: min dist, tie -> min index), reuse es storage
  float* red_d = (float*)es;           // 64*16 floats
  int*   red_i = ((int*)es) + MT * 16; // 64*16 ints
#pragma unroll
  for (int i = 0; i < 4; ++i) {
    red_d[(ty * 4 + i) * 16 + tx] = bestd[i];
    red_i[(ty * 4 + i) * 16 + tx] = besti[i];
  }
  __syncthreads();
  if (tid < MT) {
    float bd = red_d[tid * 16];
    int   bi = red_i[tid * 16];
    for (int t = 1; t < 16; ++t) {
      float d = red_d[tid * 16 + t];
      int   x = red_i[tid * 16 + t];
      if (d < bd || (d == bd && x < bi)) { bd = d; bi = x; }
    }
    e_s[tid] = bi;
    e_out[tok0 + tid] = (float)bi;   // indices exact in fp32
  }
  __syncthreads();

  // z_q gather + loss partials: 4 threads per token, 16 elems each
  {
    const int t = tid >> 2;
    const int q = tid & 3;
    const int code = e_s[t];
    const float4* cbp = (const float4*)(cb + (size_t)code * D) + q * 4;
    nfloat4* zqp = (nfloat4*)(zq_out + (size_t)(tok0 + t) * D + q * 16);
    float s = 0.f;
#pragma unroll
    for (int r = 0; r < 4; ++r) {
      float4 v = cbp[r];
      nfloat4 nv = {v.x, v.y, v.z, v.w};
      float4 zv = *(const float4*)&zs[t][q * 16 + r * 4];
      __builtin_nontemporal_store(nv, zqp + r);
      float dx = zv.x - v.x, dy = zv.y - v.y, dz2 = zv.z - v.z, dw = zv.w - v.w;
      s += dx * dx + dy * dy + dz2 * dz2 + dw * dw;
    }
    lpart[t][q] = s;
  }
  __syncthreads();
  if (tid < MT) {
    float s = lpart[tid][0] + lpart[tid][1] + lpart[tid][2] + lpart[tid][3];
    // loss_codebook + 0.25*loss_commit, both == ||z - z_q||; fl(1.25*n) == fl(n + fl(0.25n))
    loss_out[tok0 + tid] = 1.25f * sqrtf(s);
  }
}

extern "C" void kernel_launch(void* const* d_in, const int* in_sizes, int n_in,
                              void* d_out, int out_size, void* d_ws, size_t ws_size,
                              hipStream_t stream) {
  const float* z  = (const float*)d_in[0];
  const float* cb = (const float*)d_in[1];

  float* ne  = (float*)d_ws;        // K floats
  float* rne = ne + K;              // K floats

  float* out      = (float*)d_out;
  float* e_out    = out;                              // 131072
  float* zq_out   = e_out + NTOK;                     // 131072*64
  float* sim_out  = zq_out + (size_t)NTOK * D;        // 131072*1024
  float* loss_out = sim_out + (size_t)NTOK * K;       // 131072

  vq_norms<<<K / 256, 256, 0, stream>>>(cb, ne, rne);
  vq_main<<<NTOK / MT, 256, 0, stream>>>(z, cb, ne, rne, e_out, zq_out, sim_out, loss_out);
}